// Round 2
// baseline (749.162 us; speedup 1.0000x reference)
//
#include <hip/hip_runtime.h>
#include <math.h>

#define G 8
#define T 4096
#define H 1024
#define E 32
#define C 64
#define NTOK (G*T)                 // 32768 tokens
#define COMBINE_SZ ((size_t)G*T*E*C)   // 67108864

// ---------------------------------------------------------------------------
// Kernel 1: router logits GEMM (fp32 vector) + softmax + z-loss + transposed
// probs store.  Grid: NTOK/64 blocks x 256 threads.  Block = 64 tokens.
// Wave w (0..3) computes experts [8w, 8w+8) for all 64 tokens (lane = token).
// ---------------------------------------------------------------------------
__global__ __launch_bounds__(256) void k_router(
    const float* __restrict__ x, const float* __restrict__ W,
    const float* __restrict__ bias, float* __restrict__ probs_t,
    float* __restrict__ z_out)
{
    __shared__ float lt[64][33];   // [token][expert], +1 pad for bank-conflict-free col access

    const int tid  = threadIdx.x;
    const int lane = tid & 63;
    const int wv   = __builtin_amdgcn_readfirstlane(tid >> 6);  // wave id, forced SGPR
    const int tok  = blockIdx.x * 64 + lane;                    // global token
    const float* __restrict__ xr = x + (size_t)tok * H;
    const float* __restrict__ Wg = W + wv * 8;                  // experts 8wv..8wv+7

    float acc[8] = {0,0,0,0,0,0,0,0};
    for (int h = 0; h < H; h += 4) {
        const float4 xv = *(const float4*)(xr + h);
        #pragma unroll
        for (int j = 0; j < 4; ++j) {
            // wave-uniform address -> scalar loads (W cached in K$/L1)
            const float4 w0 = *(const float4*)(Wg + (h + j) * E);
            const float4 w1 = *(const float4*)(Wg + (h + j) * E + 4);
            const float xs = (j == 0) ? xv.x : (j == 1) ? xv.y : (j == 2) ? xv.z : xv.w;
            acc[0] = fmaf(xs, w0.x, acc[0]);
            acc[1] = fmaf(xs, w0.y, acc[1]);
            acc[2] = fmaf(xs, w0.z, acc[2]);
            acc[3] = fmaf(xs, w0.w, acc[3]);
            acc[4] = fmaf(xs, w1.x, acc[4]);
            acc[5] = fmaf(xs, w1.y, acc[5]);
            acc[6] = fmaf(xs, w1.z, acc[6]);
            acc[7] = fmaf(xs, w1.w, acc[7]);
        }
    }
    #pragma unroll
    for (int e = 0; e < 8; ++e) acc[e] += bias[wv * 8 + e];
    #pragma unroll
    for (int e = 0; e < 8; ++e) lt[lane][wv * 8 + e] = acc[e];
    __syncthreads();

    // softmax + z-loss: wave 0, one token per lane
    if (tid < 64) {
        float v[E];
        float m = -1e30f;
        #pragma unroll
        for (int e = 0; e < E; ++e) { v[e] = lt[tid][e]; m = fmaxf(m, v[e]); }
        float s = 0.f;
        #pragma unroll
        for (int e = 0; e < E; ++e) { v[e] = expf(v[e] - m); s += v[e]; }
        const float inv = 1.f / s;
        #pragma unroll
        for (int e = 0; e < E; ++e) lt[tid][e] = v[e] * inv;
        const float lz = m + logf(s);
        float zsq = lz * lz;
        #pragma unroll
        for (int off = 32; off; off >>= 1) zsq += __shfl_down(zsq, off, 64);
        if (tid == 0) atomicAdd(z_out, zsq * (1.0f / (float)NTOK));
    }
    __syncthreads();

    // store probs transposed: probs_t[(g*E+e)*T + t]  (coalesced per (wave,j))
    const int base = blockIdx.x * 64;
    const int g    = base >> 12;          // /T
    const int tb   = base & (T - 1);
    #pragma unroll
    for (int j = 0; j < 8; ++j) {
        const int e = wv * 8 + j;
        probs_t[((size_t)(g * E + e)) * T + tb + lane] = lt[lane][e];
    }
}

// ---------------------------------------------------------------------------
// Kernel 2: per-(g,e) top-64 over T=4096 probs with exact jax.lax.top_k
// semantics (descending, ties -> lower index), scatter into combine/dispatch.
// Key = (ordered_float(prob) << 32) | (4095 - t): unique, fully ordered.
// Grid: G*E = 256 blocks x 256 threads; 16 candidates per thread in registers.
// ---------------------------------------------------------------------------
__global__ __launch_bounds__(256) void k_topk(
    const float* __restrict__ probs_t, float* __restrict__ out)
{
    const int ge  = blockIdx.x;          // g*E + e
    const int g   = ge >> 5;
    const int e   = ge & 31;
    const int tid = threadIdx.x;
    const float* __restrict__ col = probs_t + (size_t)ge * T;

    float vals[16];
    unsigned long long keys[16];
    #pragma unroll
    for (int j = 0; j < 16; ++j) {
        const int t = j * 256 + tid;
        const float p = col[t];
        unsigned u = __float_as_uint(p);
        u = (u & 0x80000000u) ? ~u : (u | 0x80000000u);
        keys[j] = ((unsigned long long)u << 32) | (unsigned)(4095 - t);
        vals[j] = p;
    }

    __shared__ unsigned long long wmax[4];
    __shared__ unsigned long long gk;

    for (int c = 0; c < C; ++c) {
        unsigned long long kmax = 0ull;
        #pragma unroll
        for (int j = 0; j < 16; ++j) kmax = (keys[j] > kmax) ? keys[j] : kmax;
        #pragma unroll
        for (int off = 32; off; off >>= 1) {
            const unsigned long long o = __shfl_xor(kmax, off, 64);
            kmax = (o > kmax) ? o : kmax;
        }
        if ((tid & 63) == 0) wmax[tid >> 6] = kmax;
        __syncthreads();
        if (tid == 0) {
            unsigned long long m = wmax[0];
            #pragma unroll
            for (int w = 1; w < 4; ++w) m = (wmax[w] > m) ? wmax[w] : m;
            gk = m;
        }
        __syncthreads();
        const unsigned long long gkey = gk;
        #pragma unroll
        for (int j = 0; j < 16; ++j) {
            if (keys[j] == gkey) {   // unique winner
                const int t = 4095 - (int)(gkey & 0xFFFFFFFFu);
                const size_t idx = ((((size_t)g * T + t) * E + e) * C + c);
                out[idx] = vals[j];                 // combine = gate
                out[idx + COMBINE_SZ] = 1.0f;       // dispatch mask
                keys[j] = 0ull;                     // remove from candidates
            }
        }
        // gk(c) is read by all threads before barrier at top of c+1 path;
        // thread 0 only rewrites gk after the next __syncthreads().
    }
}

// ---------------------------------------------------------------------------
extern "C" void kernel_launch(void* const* d_in, const int* in_sizes, int n_in,
                              void* d_out, int out_size, void* d_ws, size_t ws_size,
                              hipStream_t stream) {
    const float* x = (const float*)d_in[0];   // [G,T,H]
    const float* W = (const float*)d_in[1];   // [H,E]
    const float* b = (const float*)d_in[2];   // [E]
    float* out     = (float*)d_out;           // combine | dispatch | z_loss
    float* probs_t = (float*)d_ws;            // [G*E, T] = 4 MB scratch

    // outputs are one-hot-sparse; zero everything (incl. z_loss slot), then scatter
    hipMemsetAsync(d_out, 0, (size_t)out_size * sizeof(float), stream);

    k_router<<<NTOK / 64, 256, 0, stream>>>(x, W, b, probs_t, out + 2 * COMBINE_SZ);
    k_topk<<<G * E, 256, 0, stream>>>(probs_t, out);
}